// Round 11
// baseline (480.696 us; speedup 1.0000x reference)
//
#include <hip/hip_runtime.h>
#include <hip/hip_bf16.h>
#include <stdint.h>

typedef __attribute__((ext_vector_type(4)))  float  f32x4;
typedef __attribute__((ext_vector_type(16))) float  f32x16;
typedef __attribute__((ext_vector_type(4)))  float  float4v;
typedef __attribute__((ext_vector_type(8)))  short  short8v;
typedef __attribute__((ext_vector_type(4)))  short  short4v;
typedef __attribute__((ext_vector_type(8)))  unsigned short ushort8v;
typedef __attribute__((ext_vector_type(4)))  unsigned short ushort4v;

#define B_   8
#define N_   2048
#define DIN  1024
#define H_   4
#define DH   256
#define QSZ  (B_ * N_ * H_ * DH)   // 16,777,216 elements per tensor

__device__ __forceinline__ unsigned short f2bf(float x) {
  union { float f; unsigned u; } v; v.f = x;
  unsigned r = v.u + 0x7fffu + ((v.u >> 16) & 1u);   // RNE
  return (unsigned short)(r >> 16);
}

__device__ __forceinline__ unsigned cvtpk(float lo, float hi) {
  unsigned r;
  asm("v_cvt_pk_bf16_f32 %0, %1, %2" : "=v"(r) : "v"(lo), "v"(hi));
  return r;
}

__device__ __forceinline__ void gload_lds16(const void* g, void* l) {
  __builtin_amdgcn_global_load_lds(
      (const __attribute__((address_space(1))) unsigned int*)g,
      (__attribute__((address_space(3))) unsigned int*)l, 16, 0, 0);
}

// ---------------------------------------------------------------------------
// Prep: Wt[c][k] = bf16(W[k][c]) for c in [0,3328): Wq|Wk|Wv cols 0..3071,
// Wo cols 3072..3327.  64x64 fp32 LDS tile transpose.
// ---------------------------------------------------------------------------
__global__ __launch_bounds__(256) void prep_wt(
    const float* __restrict__ Wq, const float* __restrict__ Wk,
    const float* __restrict__ Wv, const float* __restrict__ Wo,
    unsigned short* __restrict__ Wt)
{
  __shared__ float Lt[64][68];
  const int tid = threadIdx.x;
  const int c0 = blockIdx.x * 64;     // 0..3327
  const int k0 = blockIdx.y * 64;
  const int msel = c0 >> 10;
  const float* src = (msel == 0) ? Wq : (msel == 1) ? Wk : (msel == 2) ? Wv : Wo;
  const int stride = (msel == 3) ? 256 : 1024;
  const int cloc = c0 - msel * 1024;
  #pragma unroll
  for (int p = 0; p < 4; ++p) {
    int kr = p * 16 + (tid >> 4), c4 = (tid & 15) * 4;
    float4v v = *(const float4v*)(src + (size_t)(k0 + kr) * stride + cloc + c4);
    Lt[kr][c4 + 0] = v[0]; Lt[kr][c4 + 1] = v[1];
    Lt[kr][c4 + 2] = v[2]; Lt[kr][c4 + 3] = v[3];
  }
  __syncthreads();
  int n = tid >> 2, kc = (tid & 3) * 16;
  ushort8v h0, h1;
  #pragma unroll
  for (int j = 0; j < 8; ++j) h0[j] = f2bf(Lt[kc + j][n]);
  #pragma unroll
  for (int j = 0; j < 8; ++j) h1[j] = f2bf(Lt[kc + 8 + j][n]);
  unsigned short* dst = Wt + (size_t)(c0 + n) * 1024 + k0 + kc;
  *(ushort8v*)dst = h0;
  *(ushort8v*)(dst + 8) = h1;
}

// ---------------------------------------------------------------------------
// Kernel 1: QKV GEMM, 128m x 256n tile, BK=32, 8 waves (2m x 4n), dbuf LDS.
// Q scaled by 1/16*log2e.  V written TRANSPOSED to global: V^T[bh][d][kv].
// ---------------------------------------------------------------------------
__global__ __launch_bounds__(512) void qkv_gemm2(
    const float* __restrict__ x, const unsigned short* __restrict__ Wt,
    const float* __restrict__ bq, const float* __restrict__ bk,
    const float* __restrict__ bv, unsigned short* __restrict__ qkv)
{
  __shared__ __align__(16) unsigned short Ab[2][4096];   // [128][32] bf16
  __shared__ __align__(16) unsigned short Bb[2][8192];   // [256][32] bf16
  const int tid = threadIdx.x;
  const int lane = tid & 63, wid = tid >> 6;
  const int l15 = lane & 15, l4 = lane >> 4;

  const int id = blockIdx.x;
  const int swz = (id & 7) * 192 + (id >> 3);
  const int m0 = (swz / 12) * 128, n0 = (swz % 12) * 256;
  const int wm = (wid >> 2) * 64, wn = (wid & 3) * 64;

  const int arow = tid >> 2, akb = (tid & 3) * 16;
  const int brow1 = wid * 16 + (lane >> 2), bkb = (lane & 3) * 16;
  const float* Abase = x + (size_t)(m0 + arow) * 1024 + (akb >> 1);
  const char* Bg1 = (const char*)Wt + (size_t)(n0 + brow1) * 2048 + bkb;
  const char* Bg2 = Bg1 + 128 * 2048;

  f32x4 acc[4][4] = {};

#define QSTAGE(t, b) do {                                                    \
    float4v f0 = *(const float4v*)(Abase + (t) * 32);                        \
    float4v f1 = *(const float4v*)(Abase + (t) * 32 + 4);                    \
    gload_lds16(Bg1 + (t) * 64, (char*)&Bb[b][0] + wid * 1024);              \
    gload_lds16(Bg2 + (t) * 64, (char*)&Bb[b][0] + 8192 + wid * 1024);       \
    ushort8v hv;                                                             \
    hv[0] = f2bf(f0[0]); hv[1] = f2bf(f0[1]);                                \
    hv[2] = f2bf(f0[2]); hv[3] = f2bf(f0[3]);                                \
    hv[4] = f2bf(f1[0]); hv[5] = f2bf(f1[1]);                                \
    hv[6] = f2bf(f1[2]); hv[7] = f2bf(f1[3]);                                \
    *(ushort8v*)((char*)&Ab[b][0] + tid * 16) = hv;                          \
  } while (0)

  QSTAGE(0, 0);
  __syncthreads();

  for (int t = 0; t < 32; ++t) {
    const int cur = t & 1;
    if (t < 31) QSTAGE(t + 1, cur ^ 1);
    short8v a[4], b[4];
    #pragma unroll
    for (int mf = 0; mf < 4; ++mf)
      a[mf] = *(const short8v*)((const char*)&Ab[cur][0] +
                                (wm + mf * 16 + l15) * 64 + l4 * 16);
    #pragma unroll
    for (int nf = 0; nf < 4; ++nf)
      b[nf] = *(const short8v*)((const char*)&Bb[cur][0] +
                                (wn + nf * 16 + l15) * 64 + l4 * 16);
    #pragma unroll
    for (int mf = 0; mf < 4; ++mf)
      #pragma unroll
      for (int nf = 0; nf < 4; ++nf)
        acc[mf][nf] = __builtin_amdgcn_mfma_f32_16x16x32_bf16(a[mf], b[nf], acc[mf][nf], 0, 0, 0);
    __syncthreads();
  }
#undef QSTAGE

  const int wsel = n0 >> 10;
  const float* bias = (wsel == 0) ? bq : (wsel == 1) ? bk : bv;
  if (wsel == 2) {
    // V^T epilogue: vt[bh][d][kv], vectorized 4x bf16 along kv
    unsigned short* vt = qkv + (size_t)2 * QSZ;
    #pragma unroll
    for (int nf = 0; nf < 4; ++nf) {
      int ncl = (n0 + wn + nf * 16 + l15) & 1023;
      float bv_ = bias[ncl];
      int h = ncl >> 8, d = ncl & 255;
      #pragma unroll
      for (int mf = 0; mf < 4; ++mf) {
        int mrow0 = m0 + wm + mf * 16 + l4 * 4;
        int bb = mrow0 >> 11, nn0 = mrow0 & 2047;
        ushort4v o;
        #pragma unroll
        for (int e = 0; e < 4; ++e) o[e] = f2bf(acc[mf][nf][e] + bv_);
        *(ushort4v*)&vt[((size_t)((bb * 4 + h) * 256 + d)) * 2048 + nn0] = o;
      }
    }
  } else {
    // Q: 1/sqrt(256) * log2(e)  (exp2-domain softmax downstream)
    const float scale = (wsel == 0) ? 0.0625f * 1.44269504f : 1.0f;
    unsigned short* dst = qkv + (size_t)wsel * QSZ;
    #pragma unroll
    for (int nf = 0; nf < 4; ++nf) {
      int ncl = (n0 + wn + nf * 16 + l15) & 1023;
      float bv_ = bias[ncl];
      int h = ncl >> 8, d = ncl & 255;
      #pragma unroll
      for (int mf = 0; mf < 4; ++mf)
        #pragma unroll
        for (int e = 0; e < 4; ++e) {
          int mrow = m0 + wm + mf * 16 + l4 * 4 + e;
          int bb = mrow >> 11, nn = mrow & 2047;
          dst[((size_t)(bb * 4 + h) * 2048 + nn) * 256 + d] =
              f2bf((acc[mf][nf][e] + bv_) * scale);
        }
    }
  }
}

// ---------------------------------------------------------------------------
// Kernel 2: flash attention, 32x32x16 MFMA, att[2] cross-tile pipeline (T15):
// iteration t runs ONE fused MFMA cluster {QK^T(t) + PV(t-1)} then softmax(t).
// Online-softmax invariant holds: rescale for tile t (in softmax(t)) happens
// AFTER PV(t-1) accumulated.  Two barriers/iter: barrier1 protects V dbuf
// (PV(t-1) reads buf cur^1; VISSUE(t+1) then writes it), barrier2 publishes
// K(t+1)/V(t+1) staging.  8 waves x 32 q-rows, KVBLK=64, 128 KB dynamic LDS.
// ---------------------------------------------------------------------------
__global__ __launch_bounds__(512, 2) void attn_fused(
    unsigned short* __restrict__ qkv)
{
  extern __shared__ __align__(16) char smem[];   // 131072 bytes
  const int tid = threadIdx.x;
  const int lane = tid & 63, wid = tid >> 6;
  const int l31 = lane & 31, hi = lane >> 5;

  const int id0 = blockIdx.x;                 // 0..255
  const int swzb = (id0 & 7) * 32 + (id0 >> 3);
  const int qt = swzb & 7, bh = swzb >> 3;

  const unsigned short* Qh = qkv + (size_t)bh * (N_ * DH);
  const unsigned short* Kh = qkv + (size_t)QSZ + (size_t)bh * (N_ * DH);
  const unsigned short* Vt = qkv + (size_t)2 * QSZ + (size_t)bh * (N_ * DH);

  // Q fragments: lane provides q = q0+l31, d = st*16 + hi*8 + 0..7
  const int q0 = qt * 256 + wid * 32;
  short8v qf[16];
  #pragma unroll
  for (int st = 0; st < 16; ++st)
    qf[st] = *(const short8v*)(Qh + (size_t)(q0 + l31) * DH + st * 16 + hi * 8);

  // K staging: thread handles kv=tid>>3 (0..63), d-units {sks + 8g} (16 B ea)
  const int skv = tid >> 3, sks = tid & 7;
  const unsigned short* Kg = Kh + (size_t)skv * DH + sks * 8;
  int kdst[4];
  #pragma unroll
  for (int g = 0; g < 4; ++g)
    kdst[g] = skv * 512 + (((g * 8 + sks) ^ (skv & 7)) << 4);

  // V^T staging: linear LDS dest [256 d][64 kv]; source swizzled so that
  // LDS(row r, 16B-unit u) = global (r, u ^ (r&7)).
  int vgoff[4];
  #pragma unroll
  for (int j = 0; j < 4; ++j) {
    int r = j * 64 + wid * 8 + (lane >> 3);
    int u = lane & 7;
    vgoff[j] = r * 4096 + ((u ^ (r & 7)) << 4);
  }

  // read bases
  const int dswz = (l31 & 7) << 4;
  const int krow0 = l31 * 512;                      // kv frag 0; frag1 = +16384
  int vbs[4];
  #pragma unroll
  for (int s = 0; s < 4; ++s)
    vbs[s] = l31 * 128 + (((s * 2 + hi) ^ (l31 & 7)) << 4);

  f32x16 ot[8] = {};
  float mr = -1.0e30f, lp = 0.0f;
  short8v pb0 = {}, pb1 = {}, pb2 = {}, pb3 = {};

  ushort8v kin0, kin1, kin2, kin3;

#define KBUF(b) (smem + (b) * 32768)
#define VBUF(b) (smem + 65536 + (b) * 32768)
#define BMF32 __builtin_amdgcn_mfma_f32_32x32x16_bf16

#define KISSUE(t) do {                                                       \
    const unsigned short* kp = Kg + (size_t)(t) * (64 * DH);                 \
    kin0 = *(const ushort8v*)(kp);                                           \
    kin1 = *(const ushort8v*)(kp + 64);                                      \
    kin2 = *(const ushort8v*)(kp + 128);                                     \
    kin3 = *(const ushort8v*)(kp + 192);                                     \
  } while (0)

#define KWRITE(b) do {                                                       \
    char* kb = KBUF(b);                                                      \
    *(ushort8v*)(kb + kdst[0]) = kin0;                                       \
    *(ushort8v*)(kb + kdst[1]) = kin1;                                       \
    *(ushort8v*)(kb + kdst[2]) = kin2;                                       \
    *(ushort8v*)(kb + kdst[3]) = kin3;                                       \
  } while (0)

#define VISSUE(t, b) do {                                                    \
    const char* vg = (const char*)Vt + (size_t)(t) * 128;                    \
    _Pragma("unroll")                                                        \
    for (int j = 0; j < 4; ++j)                                              \
      gload_lds16(vg + vgoff[j], VBUF(b) + j * 8192 + wid * 1024);           \
  } while (0)

#define PVBLOCK(Vc) do {                                                     \
    _Pragma("unroll")                                                        \
    for (int df = 0; df < 8; ++df) {                                         \
      const char* vr = (Vc) + df * 4096;                                     \
      short8v v0 = *(const short8v*)(vr + vbs[0]);                           \
      short8v v1 = *(const short8v*)(vr + vbs[1]);                           \
      short8v v2 = *(const short8v*)(vr + vbs[2]);                           \
      short8v v3 = *(const short8v*)(vr + vbs[3]);                           \
      ot[df] = BMF32(v0, pb0, ot[df], 0, 0, 0);                              \
      ot[df] = BMF32(v1, pb1, ot[df], 0, 0, 0);                              \
      ot[df] = BMF32(v2, pb2, ot[df], 0, 0, 0);                              \
      ot[df] = BMF32(v3, pb3, ot[df], 0, 0, 0);                              \
    }                                                                        \
  } while (0)

  union UPK { unsigned u[4]; short8v v; };

  // prologue: stage tile 0
  KISSUE(0);
  VISSUE(0, 0);
  KWRITE(0);
  __syncthreads();

  for (int t = 0; t < 32; ++t) {
    const int cur = t & 1;
    if (t < 31) KISSUE(t + 1);              // global->reg; hides under cluster

    // ---- fused MFMA cluster: QK^T(t) + PV(t-1) ----
    const char* Kc = KBUF(cur);
    f32x16 sa = {}, sb = {};
    __builtin_amdgcn_s_setprio(1);
    #pragma unroll
    for (int st = 0; st < 16; ++st) {
      int off = (st * 32 + hi * 16) ^ dswz;
      short8v a0 = *(const short8v*)(Kc + krow0 + off);
      short8v a1 = *(const short8v*)(Kc + 16384 + krow0 + off);
      sa = BMF32(a0, qf[st], sa, 0, 0, 0);
      sb = BMF32(a1, qf[st], sb, 0, 0, 0);
    }
    if (t > 0) PVBLOCK(VBUF(cur ^ 1));      // PV(t-1), pb from softmax(t-1)
    __builtin_amdgcn_s_setprio(0);

    __syncthreads();                        // barrier1: PV reads of V(t-1) done

    if (t < 31) {
      KWRITE(cur ^ 1);                      // K(t+1) -> alt K buffer
      VISSUE(t + 1, cur ^ 1);               // V(t+1) DMA into freed V buffer
    }

    // ---- online softmax(t) (exp2 domain, row-local, 1-hop exchange) ----
    float tm = sa[0];
    #pragma unroll
    for (int i = 1; i < 16; ++i) tm = fmaxf(tm, sa[i]);
    #pragma unroll
    for (int i = 0; i < 16; ++i) tm = fmaxf(tm, sb[i]);
    tm = fmaxf(tm, __shfl_xor(tm, 32));
    if (__any(tm > mr + 11.54f)) {          // defer-max (8 nats in exp2 dom)
      float mn = fmaxf(mr, tm), al = exp2f(mr - mn);
      lp *= al;
      #pragma unroll
      for (int df = 0; df < 8; ++df) ot[df] *= al;
      mr = mn;
    }
    #pragma unroll
    for (int i = 0; i < 16; ++i) { sa[i] = exp2f(sa[i] - mr); sb[i] = exp2f(sb[i] - mr); }
    #pragma unroll
    for (int i = 0; i < 16; ++i) lp += sa[i] + sb[i];

    // ---- P -> PV B-frags: cvt_pk + permlane32_swap (T12) ----
    {
      unsigned x0 = cvtpk(sa[0], sa[1]),  y0 = cvtpk(sa[4], sa[5]);
      unsigned x1 = cvtpk(sa[2], sa[3]),  y1 = cvtpk(sa[6], sa[7]);
      unsigned x2 = cvtpk(sa[8], sa[9]),  y2 = cvtpk(sa[12], sa[13]);
      unsigned x3 = cvtpk(sa[10], sa[11]), y3 = cvtpk(sa[14], sa[15]);
      asm("v_permlane32_swap_b32 %0, %1" : "+v"(x0), "+v"(y0));
      asm("v_permlane32_swap_b32 %0, %1" : "+v"(x1), "+v"(y1));
      asm("v_permlane32_swap_b32 %0, %1" : "+v"(x2), "+v"(y2));
      asm("v_permlane32_swap_b32 %0, %1" : "+v"(x3), "+v"(y3));
      UPK u0; u0.u[0] = x0; u0.u[1] = x1; u0.u[2] = y0; u0.u[3] = y1; pb0 = u0.v;
      UPK u1; u1.u[0] = x2; u1.u[1] = x3; u1.u[2] = y2; u1.u[3] = y3; pb1 = u1.v;
    }
    {
      unsigned x0 = cvtpk(sb[0], sb[1]),  y0 = cvtpk(sb[4], sb[5]);
      unsigned x1 = cvtpk(sb[2], sb[3]),  y1 = cvtpk(sb[6], sb[7]);
      unsigned x2 = cvtpk(sb[8], sb[9]),  y2 = cvtpk(sb[12], sb[13]);
      unsigned x3 = cvtpk(sb[10], sb[11]), y3 = cvtpk(sb[14], sb[15]);
      asm("v_permlane32_swap_b32 %0, %1" : "+v"(x0), "+v"(y0));
      asm("v_permlane32_swap_b32 %0, %1" : "+v"(x1), "+v"(y1));
      asm("v_permlane32_swap_b32 %0, %1" : "+v"(x2), "+v"(y2));
      asm("v_permlane32_swap_b32 %0, %1" : "+v"(x3), "+v"(y3));
      UPK u0; u0.u[0] = x0; u0.u[1] = x1; u0.u[2] = y0; u0.u[3] = y1; pb2 = u0.v;
      UPK u1; u1.u[0] = x2; u1.u[1] = x3; u1.u[2] = y2; u1.u[3] = y3; pb3 = u1.v;
    }

    __syncthreads();                        // barrier2: staging visible
  }

  // ---- final PV(31): V(31) is in VBUF(1), pb from softmax(31) ----
  __builtin_amdgcn_s_setprio(1);
  PVBLOCK(VBUF(1));
  __builtin_amdgcn_s_setprio(0);

  // ---- epilogue: combine psum halves, normalize, overwrite own Q rows ----
  lp += __shfl_xor(lp, 32);
  float inv = 1.0f / lp;
  unsigned short* Oq = (unsigned short*)Qh;
  size_t base = (size_t)(q0 + l31) * DH;
  #pragma unroll
  for (int df = 0; df < 8; ++df) {
    #pragma unroll
    for (int j = 0; j < 4; ++j) {
      int d = df * 32 + j * 8 + hi * 4;
      ushort4v o;
      #pragma unroll
      for (int e = 0; e < 4; ++e) o[e] = f2bf(ot[df][j * 4 + e] * inv);
      *(ushort4v*)&Oq[base + d] = o;
    }
  }
#undef KISSUE
#undef KWRITE
#undef VISSUE
#undef PVBLOCK
#undef KBUF
#undef VBUF
#undef BMF32
}

// ---------------------------------------------------------------------------
// Kernel 3: out[16384][256] = attnO @ Wo + bo.  attnO is in the Q region,
// layout [B,H,N,DH]; logical row m = bb*2048+q, col k = h*256+d.
// 64m x 256n tiles -> 256 blocks (all CUs), 4 waves, 40 KB LDS.
// ---------------------------------------------------------------------------
__global__ __launch_bounds__(256) void out_gemm3(
    const unsigned short* __restrict__ Aq, const unsigned short* __restrict__ WoT,
    const float* __restrict__ bo, float* __restrict__ out)
{
  __shared__ __align__(16) unsigned short Ab[2][2048];   // [64][32] bf16
  __shared__ __align__(16) unsigned short Bb[2][8192];   // [256][32] bf16
  const int tid = threadIdx.x;
  const int lane = tid & 63, wid = tid >> 6;   // 4 waves
  const int l15 = lane & 15, l4 = lane >> 4;
  const int m0 = blockIdx.x * 64;
  const int wn = wid * 64;
  const int bb = m0 >> 11;
  const int qbase = m0 & 2047;
  const int sr = lane >> 2, sc = lane & 3;

  f32x4 acc[4][4] = {};

#define OSTAGE(t, b) do {                                                    \
    int h = (t) >> 3;                                                        \
    int d0 = ((t) & 7) * 32 + sc * 8;                                        \
    gload_lds16(Aq + ((size_t)(bb * 4 + h) * 2048 + qbase + wid * 16 + sr)   \
                         * 256 + d0,                                         \
                (char*)&Ab[b][0] + wid * 1024);                              \
    _Pragma("unroll")                                                        \
    for (int i = 0; i < 4; ++i) {                                            \
      int br = wid * 64 + i * 16 + sr;                                       \
      gload_lds16((const char*)WoT + (size_t)br * 2048 + (t) * 64 + sc * 16, \
                  (char*)&Bb[b][0] + (wid * 4 + i) * 1024);                  \
    }                                                                        \
  } while (0)

  OSTAGE(0, 0);
  __syncthreads();

  for (int t = 0; t < 32; ++t) {
    const int cur = t & 1;
    if (t < 31) OSTAGE(t + 1, cur ^ 1);
    short8v a[4], b[4];
    #pragma unroll
    for (int mf = 0; mf < 4; ++mf)
      a[mf] = *(const short8v*)((const char*)&Ab[cur][0] +
                                (mf * 16 + l15) * 64 + l4 * 16);
    #pragma unroll
    for (int nf = 0; nf < 4; ++nf)
      b[nf] = *(const short8v*)((const char*)&Bb[cur][0] +
                                (wn + nf * 16 + l15) * 64 + l4 * 16);
    #pragma unroll
    for (int mf = 0; mf < 4; ++mf)
      #pragma unroll
      for (int nf = 0; nf < 4; ++nf)
        acc[mf][nf] = __builtin_amdgcn_mfma_f32_16x16x32_bf16(a[mf], b[nf], acc[mf][nf], 0, 0, 0);
    __syncthreads();
  }
#undef OSTAGE

  #pragma unroll
  for (int nf = 0; nf < 4; ++nf) {
    int ncol = wn + nf * 16 + l15;
    float bv_ = bo[ncol];
    #pragma unroll
    for (int mf = 0; mf < 4; ++mf)
      #pragma unroll
      for (int e = 0; e < 4; ++e) {
        int mrow = m0 + mf * 16 + l4 * 4 + e;
        out[(size_t)mrow * 256 + ncol] = acc[mf][nf][e] + bv_;
      }
  }
}

// ---------------------------------------------------------------------------
extern "C" void kernel_launch(void* const* d_in, const int* in_sizes, int n_in,
                              void* d_out, int out_size, void* d_ws, size_t ws_size,
                              hipStream_t stream) {
  const float* x  = (const float*)d_in[0];
  const float* Wq = (const float*)d_in[1];
  const float* bq = (const float*)d_in[2];
  const float* Wk = (const float*)d_in[3];
  const float* bk = (const float*)d_in[4];
  const float* Wv = (const float*)d_in[5];
  const float* bv = (const float*)d_in[6];
  const float* Wo = (const float*)d_in[7];
  const float* bo = (const float*)d_in[8];

  unsigned short* qkvbuf = (unsigned short*)d_ws;       // Q|K|V^T bf16 (96 MiB)
  unsigned short* Wt     = qkvbuf + (size_t)3 * QSZ;    // [3328][1024] bf16
  float* out = (float*)d_out;

  prep_wt  <<<dim3(52, 16), 256, 0, stream>>>(Wq, Wk, Wv, Wo, Wt);
  qkv_gemm2<<<dim3(1536),   512, 0, stream>>>(x, Wt, bq, bk, bv, qkvbuf);
  attn_fused<<<dim3(256),   512, 131072, stream>>>(qkvbuf);
  out_gemm3<<<dim3(256),    256, 0, stream>>>(qkvbuf, Wt + (size_t)3072 * 1024, bo, out);
}

// Round 12
// 340.523 us; speedup vs baseline: 1.4116x; 1.4116x over previous
//
#include <hip/hip_runtime.h>
#include <hip/hip_bf16.h>
#include <stdint.h>

typedef __attribute__((ext_vector_type(4)))  float  f32x4;
typedef __attribute__((ext_vector_type(16))) float  f32x16;
typedef __attribute__((ext_vector_type(4)))  float  float4v;
typedef __attribute__((ext_vector_type(8)))  short  short8v;
typedef __attribute__((ext_vector_type(4)))  short  short4v;
typedef __attribute__((ext_vector_type(8)))  unsigned short ushort8v;
typedef __attribute__((ext_vector_type(4)))  unsigned short ushort4v;

#define B_   8
#define N_   2048
#define DIN  1024
#define H_   4
#define DH   256
#define QSZ  (B_ * N_ * H_ * DH)   // 16,777,216 elements per tensor

__device__ __forceinline__ unsigned short f2bf(float x) {
  union { float f; unsigned u; } v; v.f = x;
  unsigned r = v.u + 0x7fffu + ((v.u >> 16) & 1u);   // RNE
  return (unsigned short)(r >> 16);
}

__device__ __forceinline__ unsigned cvtpk(float lo, float hi) {
  unsigned r;
  asm("v_cvt_pk_bf16_f32 %0, %1, %2" : "=v"(r) : "v"(lo), "v"(hi));
  return r;
}

__device__ __forceinline__ void gload_lds16(const void* g, void* l) {
  __builtin_amdgcn_global_load_lds(
      (const __attribute__((address_space(1))) unsigned int*)g,
      (__attribute__((address_space(3))) unsigned int*)l, 16, 0, 0);
}

// ---------------------------------------------------------------------------
// Prep: Wt[c][k] = bf16(W[k][c]) for c in [0,3328): Wq|Wk|Wv cols 0..3071,
// Wo cols 3072..3327.  64x64 fp32 LDS tile transpose.
// ---------------------------------------------------------------------------
__global__ __launch_bounds__(256) void prep_wt(
    const float* __restrict__ Wq, const float* __restrict__ Wk,
    const float* __restrict__ Wv, const float* __restrict__ Wo,
    unsigned short* __restrict__ Wt)
{
  __shared__ float Lt[64][68];
  const int tid = threadIdx.x;
  const int c0 = blockIdx.x * 64;     // 0..3327
  const int k0 = blockIdx.y * 64;
  const int msel = c0 >> 10;
  const float* src = (msel == 0) ? Wq : (msel == 1) ? Wk : (msel == 2) ? Wv : Wo;
  const int stride = (msel == 3) ? 256 : 1024;
  const int cloc = c0 - msel * 1024;
  #pragma unroll
  for (int p = 0; p < 4; ++p) {
    int kr = p * 16 + (tid >> 4), c4 = (tid & 15) * 4;
    float4v v = *(const float4v*)(src + (size_t)(k0 + kr) * stride + cloc + c4);
    Lt[kr][c4 + 0] = v[0]; Lt[kr][c4 + 1] = v[1];
    Lt[kr][c4 + 2] = v[2]; Lt[kr][c4 + 3] = v[3];
  }
  __syncthreads();
  int n = tid >> 2, kc = (tid & 3) * 16;
  ushort8v h0, h1;
  #pragma unroll
  for (int j = 0; j < 8; ++j) h0[j] = f2bf(Lt[kc + j][n]);
  #pragma unroll
  for (int j = 0; j < 8; ++j) h1[j] = f2bf(Lt[kc + 8 + j][n]);
  unsigned short* dst = Wt + (size_t)(c0 + n) * 1024 + k0 + kc;
  *(ushort8v*)dst = h0;
  *(ushort8v*)(dst + 8) = h1;
}

// ---------------------------------------------------------------------------
// Kernel 1: QKV GEMM, 128m x 256n tile, BK=32, 8 waves (2m x 4n), dbuf LDS.
// Q scaled by 1/16*log2e.  V written TRANSPOSED to global: V^T[bh][d][kv].
// ---------------------------------------------------------------------------
__global__ __launch_bounds__(512) void qkv_gemm2(
    const float* __restrict__ x, const unsigned short* __restrict__ Wt,
    const float* __restrict__ bq, const float* __restrict__ bk,
    const float* __restrict__ bv, unsigned short* __restrict__ qkv)
{
  __shared__ __align__(16) unsigned short Ab[2][4096];   // [128][32] bf16
  __shared__ __align__(16) unsigned short Bb[2][8192];   // [256][32] bf16
  const int tid = threadIdx.x;
  const int lane = tid & 63, wid = tid >> 6;
  const int l15 = lane & 15, l4 = lane >> 4;

  const int id = blockIdx.x;
  const int swz = (id & 7) * 192 + (id >> 3);
  const int m0 = (swz / 12) * 128, n0 = (swz % 12) * 256;
  const int wm = (wid >> 2) * 64, wn = (wid & 3) * 64;

  const int arow = tid >> 2, akb = (tid & 3) * 16;
  const int brow1 = wid * 16 + (lane >> 2), bkb = (lane & 3) * 16;
  const float* Abase = x + (size_t)(m0 + arow) * 1024 + (akb >> 1);
  const char* Bg1 = (const char*)Wt + (size_t)(n0 + brow1) * 2048 + bkb;
  const char* Bg2 = Bg1 + 128 * 2048;

  f32x4 acc[4][4] = {};

#define QSTAGE(t, b) do {                                                    \
    float4v f0 = *(const float4v*)(Abase + (t) * 32);                        \
    float4v f1 = *(const float4v*)(Abase + (t) * 32 + 4);                    \
    gload_lds16(Bg1 + (t) * 64, (char*)&Bb[b][0] + wid * 1024);              \
    gload_lds16(Bg2 + (t) * 64, (char*)&Bb[b][0] + 8192 + wid * 1024);       \
    ushort8v hv;                                                             \
    hv[0] = f2bf(f0[0]); hv[1] = f2bf(f0[1]);                                \
    hv[2] = f2bf(f0[2]); hv[3] = f2bf(f0[3]);                                \
    hv[4] = f2bf(f1[0]); hv[5] = f2bf(f1[1]);                                \
    hv[6] = f2bf(f1[2]); hv[7] = f2bf(f1[3]);                                \
    *(ushort8v*)((char*)&Ab[b][0] + tid * 16) = hv;                          \
  } while (0)

  QSTAGE(0, 0);
  __syncthreads();

  for (int t = 0; t < 32; ++t) {
    const int cur = t & 1;
    if (t < 31) QSTAGE(t + 1, cur ^ 1);
    short8v a[4], b[4];
    #pragma unroll
    for (int mf = 0; mf < 4; ++mf)
      a[mf] = *(const short8v*)((const char*)&Ab[cur][0] +
                                (wm + mf * 16 + l15) * 64 + l4 * 16);
    #pragma unroll
    for (int nf = 0; nf < 4; ++nf)
      b[nf] = *(const short8v*)((const char*)&Bb[cur][0] +
                                (wn + nf * 16 + l15) * 64 + l4 * 16);
    #pragma unroll
    for (int mf = 0; mf < 4; ++mf)
      #pragma unroll
      for (int nf = 0; nf < 4; ++nf)
        acc[mf][nf] = __builtin_amdgcn_mfma_f32_16x16x32_bf16(a[mf], b[nf], acc[mf][nf], 0, 0, 0);
    __syncthreads();
  }
#undef QSTAGE

  const int wsel = n0 >> 10;
  const float* bias = (wsel == 0) ? bq : (wsel == 1) ? bk : bv;
  if (wsel == 2) {
    // V^T epilogue: vt[bh][d][kv], vectorized 4x bf16 along kv
    unsigned short* vt = qkv + (size_t)2 * QSZ;
    #pragma unroll
    for (int nf = 0; nf < 4; ++nf) {
      int ncl = (n0 + wn + nf * 16 + l15) & 1023;
      float bv_ = bias[ncl];
      int h = ncl >> 8, d = ncl & 255;
      #pragma unroll
      for (int mf = 0; mf < 4; ++mf) {
        int mrow0 = m0 + wm + mf * 16 + l4 * 4;
        int bb = mrow0 >> 11, nn0 = mrow0 & 2047;
        ushort4v o;
        #pragma unroll
        for (int e = 0; e < 4; ++e) o[e] = f2bf(acc[mf][nf][e] + bv_);
        *(ushort4v*)&vt[((size_t)((bb * 4 + h) * 256 + d)) * 2048 + nn0] = o;
      }
    }
  } else {
    // Q: 1/sqrt(256) * log2(e)  (exp2-domain softmax downstream)
    const float scale = (wsel == 0) ? 0.0625f * 1.44269504f : 1.0f;
    unsigned short* dst = qkv + (size_t)wsel * QSZ;
    #pragma unroll
    for (int nf = 0; nf < 4; ++nf) {
      int ncl = (n0 + wn + nf * 16 + l15) & 1023;
      float bv_ = bias[ncl];
      int h = ncl >> 8, d = ncl & 255;
      #pragma unroll
      for (int mf = 0; mf < 4; ++mf)
        #pragma unroll
        for (int e = 0; e < 4; ++e) {
          int mrow = m0 + wm + mf * 16 + l4 * 4 + e;
          int bb = mrow >> 11, nn = mrow & 2047;
          dst[((size_t)(bb * 4 + h) * 2048 + nn) * 256 + d] =
              f2bf((acc[mf][nf][e] + bv_) * scale);
        }
    }
  }
}

// ---------------------------------------------------------------------------
// Kernel 2: flash attention, 32x32x16 MFMA, R10 schedule, 2 blocks/CU.
// 4 waves x 32 q-rows (128 q/block), KVBLK=32, 64 KB dynamic LDS ->
// 2 independent blocks per CU (independent barriers overlap drains).
// K: reg-staged, row-XOR swizzle, b128 frag reads.  V: V^T[d][kv] global ->
// linear LDS DMA, source swizzle over 4-unit rows (2-way max = free).
// Output written in place over the block's own Q rows.
// ---------------------------------------------------------------------------
__global__ __launch_bounds__(256, 2) void attn_fused(
    unsigned short* __restrict__ qkv)
{
  extern __shared__ __align__(16) char smem[];   // 65536 bytes
  const int tid = threadIdx.x;
  const int lane = tid & 63, wid = tid >> 6;     // 4 waves
  const int l31 = lane & 31, hi = lane >> 5;

  const int id0 = blockIdx.x;                 // 0..511
  const int swzb = (id0 & 7) * 64 + (id0 >> 3);
  const int qt = swzb & 15, bh = swzb >> 4;   // 16 qt x 32 bh

  const unsigned short* Qh = qkv + (size_t)bh * (N_ * DH);
  const unsigned short* Kh = qkv + (size_t)QSZ + (size_t)bh * (N_ * DH);
  const unsigned short* Vt = qkv + (size_t)2 * QSZ + (size_t)bh * (N_ * DH);

  // Q fragments: lane provides q = q0+l31, d = st*16 + hi*8 + 0..7
  const int q0 = qt * 128 + wid * 32;
  short8v qf[16];
  #pragma unroll
  for (int st = 0; st < 16; ++st)
    qf[st] = *(const short8v*)(Qh + (size_t)(q0 + l31) * DH + st * 16 + hi * 8);

  // K staging: thread handles kv=tid>>3 (0..31), d-units {sks + 8g} (16 B ea)
  const int skv = tid >> 3, sks = tid & 7;
  const unsigned short* Kg = Kh + (size_t)skv * DH + sks * 8;
  int kdst[4];
  #pragma unroll
  for (int g = 0; g < 4; ++g)
    kdst[g] = skv * 512 + (((g * 8 + sks) ^ (skv & 7)) << 4);

  // V^T staging: linear LDS dest [256 d][32 kv]; source swizzled so that
  // LDS(row r, 16B-unit u) = global (r, u ^ (r&3)); rows are 4 units (64 B).
  int vgoff[4];
  #pragma unroll
  for (int j = 0; j < 4; ++j) {
    int r = j * 64 + (tid >> 2);
    int u = tid & 3;
    vgoff[j] = r * 4096 + ((u ^ (r & 3)) << 4);
  }

  // read bases
  const int dswz = (l31 & 7) << 4;
  const int krow0 = l31 * 512;
  int vbs[2];
  #pragma unroll
  for (int s = 0; s < 2; ++s)
    vbs[s] = l31 * 64 + (((s * 2 + hi) ^ (l31 & 3)) << 4);

  f32x16 ot[8] = {};
  float mr = -1.0e30f, lp = 0.0f;

  ushort8v kin0, kin1, kin2, kin3;

#define KBUF(b) (smem + (b) * 16384)
#define VBUF(b) (smem + 32768 + (b) * 16384)
#define BMF32 __builtin_amdgcn_mfma_f32_32x32x16_bf16

#define KISSUE(t) do {                                                       \
    const unsigned short* kp = Kg + (size_t)(t) * (32 * DH);                 \
    kin0 = *(const ushort8v*)(kp);                                           \
    kin1 = *(const ushort8v*)(kp + 64);                                      \
    kin2 = *(const ushort8v*)(kp + 128);                                     \
    kin3 = *(const ushort8v*)(kp + 192);                                     \
  } while (0)

#define KWRITE(b) do {                                                       \
    char* kb = KBUF(b);                                                      \
    *(ushort8v*)(kb + kdst[0]) = kin0;                                       \
    *(ushort8v*)(kb + kdst[1]) = kin1;                                       \
    *(ushort8v*)(kb + kdst[2]) = kin2;                                       \
    *(ushort8v*)(kb + kdst[3]) = kin3;                                       \
  } while (0)

#define VISSUE(t, b) do {                                                    \
    const char* vg = (const char*)Vt + (size_t)(t) * 64;                     \
    _Pragma("unroll")                                                        \
    for (int j = 0; j < 4; ++j)                                              \
      gload_lds16(vg + vgoff[j], VBUF(b) + j * 4096 + tid * 16);             \
  } while (0)

  union UPK { unsigned u[4]; short8v v; };

  // prologue: stage tile 0
  KISSUE(0);
  VISSUE(0, 0);
  KWRITE(0);
  __syncthreads();

  for (int t = 0; t < 64; ++t) {
    const int cur = t & 1;
    if (t < 63) VISSUE(t + 1, cur ^ 1);     // fire-and-forget DMA

    // ---- QK^T: S^T = K . Q^T, 1 kv-frag x 16 d-steps = 16 MFMAs ----
    const char* Kc = KBUF(cur);
    f32x16 sa = {};
    __builtin_amdgcn_s_setprio(1);
    #pragma unroll
    for (int st = 0; st < 16; ++st) {
      int off = (st * 32 + hi * 16) ^ dswz;
      short8v a0 = *(const short8v*)(Kc + krow0 + off);
      sa = BMF32(a0, qf[st], sa, 0, 0, 0);
    }
    __builtin_amdgcn_s_setprio(0);

    if (t < 63) KISSUE(t + 1);              // K(t+1) global->reg

    // ---- online softmax (exp2 domain, row-local, 1-hop exchange) ----
    float tm = sa[0];
    #pragma unroll
    for (int i = 1; i < 16; ++i) tm = fmaxf(tm, sa[i]);
    tm = fmaxf(tm, __shfl_xor(tm, 32));
    if (__any(tm > mr + 11.54f)) {          // defer-max (8 nats in exp2 dom)
      float mn = fmaxf(mr, tm), al = exp2f(mr - mn);
      lp *= al;
      #pragma unroll
      for (int df = 0; df < 8; ++df) ot[df] *= al;
      mr = mn;
    }
    #pragma unroll
    for (int i = 0; i < 16; ++i) sa[i] = exp2f(sa[i] - mr);
    #pragma unroll
    for (int i = 0; i < 16; ++i) lp += sa[i];

    // ---- P -> PV B-frags: cvt_pk + permlane32_swap (T12) ----
    short8v pb0, pb1;
    {
      unsigned x0 = cvtpk(sa[0], sa[1]),  y0 = cvtpk(sa[4], sa[5]);
      unsigned x1 = cvtpk(sa[2], sa[3]),  y1 = cvtpk(sa[6], sa[7]);
      unsigned x2 = cvtpk(sa[8], sa[9]),  y2 = cvtpk(sa[12], sa[13]);
      unsigned x3 = cvtpk(sa[10], sa[11]), y3 = cvtpk(sa[14], sa[15]);
      asm("v_permlane32_swap_b32 %0, %1" : "+v"(x0), "+v"(y0));
      asm("v_permlane32_swap_b32 %0, %1" : "+v"(x1), "+v"(y1));
      asm("v_permlane32_swap_b32 %0, %1" : "+v"(x2), "+v"(y2));
      asm("v_permlane32_swap_b32 %0, %1" : "+v"(x3), "+v"(y3));
      UPK u0; u0.u[0] = x0; u0.u[1] = x1; u0.u[2] = y0; u0.u[3] = y1; pb0 = u0.v;
      UPK u1; u1.u[0] = x2; u1.u[1] = x3; u1.u[2] = y2; u1.u[3] = y3; pb1 = u1.v;
    }

    // ---- PV: O^T += V^T . P^T, 8 d-frags x 2 kv-steps = 16 MFMAs ----
    const char* Vc = VBUF(cur);
    __builtin_amdgcn_s_setprio(1);
    #pragma unroll
    for (int df = 0; df < 8; ++df) {
      const char* vr = Vc + df * 2048;
      short8v v0 = *(const short8v*)(vr + vbs[0]);
      short8v v1 = *(const short8v*)(vr + vbs[1]);
      ot[df] = BMF32(v0, pb0, ot[df], 0, 0, 0);
      ot[df] = BMF32(v1, pb1, ot[df], 0, 0, 0);
    }
    __builtin_amdgcn_s_setprio(0);

    if (t < 63) KWRITE(cur ^ 1);            // K(t+1) -> alt buffer

    __syncthreads();   // drains vmcnt/lgkm: tile t+1 staged & visible
  }

  // ---- epilogue: combine psum halves, normalize, overwrite own Q rows ----
  lp += __shfl_xor(lp, 32);
  float inv = 1.0f / lp;
  unsigned short* Oq = (unsigned short*)Qh;
  size_t base = (size_t)(q0 + l31) * DH;
  #pragma unroll
  for (int df = 0; df < 8; ++df) {
    #pragma unroll
    for (int j = 0; j < 4; ++j) {
      int d = df * 32 + j * 8 + hi * 4;
      ushort4v o;
      #pragma unroll
      for (int e = 0; e < 4; ++e) o[e] = f2bf(ot[df][j * 4 + e] * inv);
      *(ushort4v*)&Oq[base + d] = o;
    }
  }
#undef KISSUE
#undef KWRITE
#undef VISSUE
#undef KBUF
#undef VBUF
#undef BMF32
}

// ---------------------------------------------------------------------------
// Kernel 3: out[16384][256] = attnO @ Wo + bo.  attnO is in the Q region,
// layout [B,H,N,DH]; logical row m = bb*2048+q, col k = h*256+d.
// 64m x 256n tiles -> 256 blocks (all CUs), 4 waves, 40 KB LDS.
// ---------------------------------------------------------------------------
__global__ __launch_bounds__(256) void out_gemm3(
    const unsigned short* __restrict__ Aq, const unsigned short* __restrict__ WoT,
    const float* __restrict__ bo, float* __restrict__ out)
{
  __shared__ __align__(16) unsigned short Ab[2][2048];   // [64][32] bf16
  __shared__ __align__(16) unsigned short Bb[2][8192];   // [256][32] bf16
  const int tid = threadIdx.x;
  const int lane = tid & 63, wid = tid >> 6;   // 4 waves
  const int l15 = lane & 15, l4 = lane >> 4;
  const int m0 = blockIdx.x * 64;
  const int wn = wid * 64;
  const int bb = m0 >> 11;
  const int qbase = m0 & 2047;
  const int sr = lane >> 2, sc = lane & 3;

  f32x4 acc[4][4] = {};

#define OSTAGE(t, b) do {                                                    \
    int h = (t) >> 3;                                                        \
    int d0 = ((t) & 7) * 32 + sc * 8;                                        \
    gload_lds16(Aq + ((size_t)(bb * 4 + h) * 2048 + qbase + wid * 16 + sr)   \
                         * 256 + d0,                                         \
                (char*)&Ab[b][0] + wid * 1024);                              \
    _Pragma("unroll")                                                        \
    for (int i = 0; i < 4; ++i) {                                            \
      int br = wid * 64 + i * 16 + sr;                                       \
      gload_lds16((const char*)WoT + (size_t)br * 2048 + (t) * 64 + sc * 16, \
                  (char*)&Bb[b][0] + (wid * 4 + i) * 1024);                  \
    }                                                                        \
  } while (0)

  OSTAGE(0, 0);
  __syncthreads();

  for (int t = 0; t < 32; ++t) {
    const int cur = t & 1;
    if (t < 31) OSTAGE(t + 1, cur ^ 1);
    short8v a[4], b[4];
    #pragma unroll
    for (int mf = 0; mf < 4; ++mf)
      a[mf] = *(const short8v*)((const char*)&Ab[cur][0] +
                                (mf * 16 + l15) * 64 + l4 * 16);
    #pragma unroll
    for (int nf = 0; nf < 4; ++nf)
      b[nf] = *(const short8v*)((const char*)&Bb[cur][0] +
                                (wn + nf * 16 + l15) * 64 + l4 * 16);
    #pragma unroll
    for (int mf = 0; mf < 4; ++mf)
      #pragma unroll
      for (int nf = 0; nf < 4; ++nf)
        acc[mf][nf] = __builtin_amdgcn_mfma_f32_16x16x32_bf16(a[mf], b[nf], acc[mf][nf], 0, 0, 0);
    __syncthreads();
  }
#undef OSTAGE

  #pragma unroll
  for (int nf = 0; nf < 4; ++nf) {
    int ncol = wn + nf * 16 + l15;
    float bv_ = bo[ncol];
    #pragma unroll
    for (int mf = 0; mf < 4; ++mf)
      #pragma unroll
      for (int e = 0; e < 4; ++e) {
        int mrow = m0 + mf * 16 + l4 * 4 + e;
        out[(size_t)mrow * 256 + ncol] = acc[mf][nf][e] + bv_;
      }
  }
}

// ---------------------------------------------------------------------------
extern "C" void kernel_launch(void* const* d_in, const int* in_sizes, int n_in,
                              void* d_out, int out_size, void* d_ws, size_t ws_size,
                              hipStream_t stream) {
  const float* x  = (const float*)d_in[0];
  const float* Wq = (const float*)d_in[1];
  const float* bq = (const float*)d_in[2];
  const float* Wk = (const float*)d_in[3];
  const float* bk = (const float*)d_in[4];
  const float* Wv = (const float*)d_in[5];
  const float* bv = (const float*)d_in[6];
  const float* Wo = (const float*)d_in[7];
  const float* bo = (const float*)d_in[8];

  unsigned short* qkvbuf = (unsigned short*)d_ws;       // Q|K|V^T bf16 (96 MiB)
  unsigned short* Wt     = qkvbuf + (size_t)3 * QSZ;    // [3328][1024] bf16
  float* out = (float*)d_out;

  prep_wt  <<<dim3(52, 16), 256, 0, stream>>>(Wq, Wk, Wv, Wo, Wt);
  qkv_gemm2<<<dim3(1536),   512, 0, stream>>>(x, Wt, bq, bk, bv, qkvbuf);
  attn_fused<<<dim3(512),   256, 65536, stream>>>(qkvbuf);
  out_gemm3<<<dim3(256),    256, 0, stream>>>(qkvbuf, Wt + (size_t)3072 * 1024, bo, out);
}

// Round 14
// 320.602 us; speedup vs baseline: 1.4994x; 1.0621x over previous
//
#include <hip/hip_runtime.h>
#include <hip/hip_bf16.h>
#include <stdint.h>

typedef __attribute__((ext_vector_type(4)))  float  f32x4;
typedef __attribute__((ext_vector_type(16))) float  f32x16;
typedef __attribute__((ext_vector_type(4)))  float  float4v;
typedef __attribute__((ext_vector_type(8)))  short  short8v;
typedef __attribute__((ext_vector_type(4)))  short  short4v;
typedef __attribute__((ext_vector_type(8)))  unsigned short ushort8v;
typedef __attribute__((ext_vector_type(4)))  unsigned short ushort4v;

#define B_   8
#define N_   2048
#define DIN  1024
#define H_   4
#define DH   256
#define QSZ  (B_ * N_ * H_ * DH)   // 16,777,216 elements per tensor

__device__ __forceinline__ unsigned short f2bf(float x) {
  union { float f; unsigned u; } v; v.f = x;
  unsigned r = v.u + 0x7fffu + ((v.u >> 16) & 1u);   // RNE
  return (unsigned short)(r >> 16);
}

__device__ __forceinline__ unsigned cvtpk(float lo, float hi) {
  unsigned r;
  asm("v_cvt_pk_bf16_f32 %0, %1, %2" : "=v"(r) : "v"(lo), "v"(hi));
  return r;
}

__device__ __forceinline__ void gload_lds16(const void* g, void* l) {
  __builtin_amdgcn_global_load_lds(
      (const __attribute__((address_space(1))) unsigned int*)g,
      (__attribute__((address_space(3))) unsigned int*)l, 16, 0, 0);
}

// ---------------------------------------------------------------------------
// Prep: Wt[c][k] = bf16(W[k][c]) for c in [0,3328): Wq|Wk|Wv cols 0..3071,
// Wo cols 3072..3327.  64x64 fp32 LDS tile transpose.
// ---------------------------------------------------------------------------
__global__ __launch_bounds__(256) void prep_wt(
    const float* __restrict__ Wq, const float* __restrict__ Wk,
    const float* __restrict__ Wv, const float* __restrict__ Wo,
    unsigned short* __restrict__ Wt)
{
  __shared__ float Lt[64][68];
  const int tid = threadIdx.x;
  const int c0 = blockIdx.x * 64;     // 0..3327
  const int k0 = blockIdx.y * 64;
  const int msel = c0 >> 10;
  const float* src = (msel == 0) ? Wq : (msel == 1) ? Wk : (msel == 2) ? Wv : Wo;
  const int stride = (msel == 3) ? 256 : 1024;
  const int cloc = c0 - msel * 1024;
  #pragma unroll
  for (int p = 0; p < 4; ++p) {
    int kr = p * 16 + (tid >> 4), c4 = (tid & 15) * 4;
    float4v v = *(const float4v*)(src + (size_t)(k0 + kr) * stride + cloc + c4);
    Lt[kr][c4 + 0] = v[0]; Lt[kr][c4 + 1] = v[1];
    Lt[kr][c4 + 2] = v[2]; Lt[kr][c4 + 3] = v[3];
  }
  __syncthreads();
  int n = tid >> 2, kc = (tid & 3) * 16;
  ushort8v h0, h1;
  #pragma unroll
  for (int j = 0; j < 8; ++j) h0[j] = f2bf(Lt[kc + j][n]);
  #pragma unroll
  for (int j = 0; j < 8; ++j) h1[j] = f2bf(Lt[kc + 8 + j][n]);
  unsigned short* dst = Wt + (size_t)(c0 + n) * 1024 + k0 + kc;
  *(ushort8v*)dst = h0;
  *(ushort8v*)(dst + 8) = h1;
}

// ---------------------------------------------------------------------------
// Kernel 1: QKV GEMM, 128m x 256n tile, BK=32, 8 waves (2m x 4n), dbuf LDS.
// Q scaled by 1/16*log2e.  V written TRANSPOSED to global: V^T[bh][d][kv].
// ---------------------------------------------------------------------------
__global__ __launch_bounds__(512) void qkv_gemm2(
    const float* __restrict__ x, const unsigned short* __restrict__ Wt,
    const float* __restrict__ bq, const float* __restrict__ bk,
    const float* __restrict__ bv, unsigned short* __restrict__ qkv)
{
  __shared__ __align__(16) unsigned short Ab[2][4096];   // [128][32] bf16
  __shared__ __align__(16) unsigned short Bb[2][8192];   // [256][32] bf16
  const int tid = threadIdx.x;
  const int lane = tid & 63, wid = tid >> 6;
  const int l15 = lane & 15, l4 = lane >> 4;

  const int id = blockIdx.x;
  const int swz = (id & 7) * 192 + (id >> 3);
  const int m0 = (swz / 12) * 128, n0 = (swz % 12) * 256;
  const int wm = (wid >> 2) * 64, wn = (wid & 3) * 64;

  const int arow = tid >> 2, akb = (tid & 3) * 16;
  const int brow1 = wid * 16 + (lane >> 2), bkb = (lane & 3) * 16;
  const float* Abase = x + (size_t)(m0 + arow) * 1024 + (akb >> 1);
  const char* Bg1 = (const char*)Wt + (size_t)(n0 + brow1) * 2048 + bkb;
  const char* Bg2 = Bg1 + 128 * 2048;

  f32x4 acc[4][4] = {};

#define QSTAGE(t, b) do {                                                    \
    float4v f0 = *(const float4v*)(Abase + (t) * 32);                        \
    float4v f1 = *(const float4v*)(Abase + (t) * 32 + 4);                    \
    gload_lds16(Bg1 + (t) * 64, (char*)&Bb[b][0] + wid * 1024);              \
    gload_lds16(Bg2 + (t) * 64, (char*)&Bb[b][0] + 8192 + wid * 1024);       \
    ushort8v hv;                                                             \
    hv[0] = f2bf(f0[0]); hv[1] = f2bf(f0[1]);                                \
    hv[2] = f2bf(f0[2]); hv[3] = f2bf(f0[3]);                                \
    hv[4] = f2bf(f1[0]); hv[5] = f2bf(f1[1]);                                \
    hv[6] = f2bf(f1[2]); hv[7] = f2bf(f1[3]);                                \
    *(ushort8v*)((char*)&Ab[b][0] + tid * 16) = hv;                          \
  } while (0)

  QSTAGE(0, 0);
  __syncthreads();

  for (int t = 0; t < 32; ++t) {
    const int cur = t & 1;
    if (t < 31) QSTAGE(t + 1, cur ^ 1);
    short8v a[4], b[4];
    #pragma unroll
    for (int mf = 0; mf < 4; ++mf)
      a[mf] = *(const short8v*)((const char*)&Ab[cur][0] +
                                (wm + mf * 16 + l15) * 64 + l4 * 16);
    #pragma unroll
    for (int nf = 0; nf < 4; ++nf)
      b[nf] = *(const short8v*)((const char*)&Bb[cur][0] +
                                (wn + nf * 16 + l15) * 64 + l4 * 16);
    #pragma unroll
    for (int mf = 0; mf < 4; ++mf)
      #pragma unroll
      for (int nf = 0; nf < 4; ++nf)
        acc[mf][nf] = __builtin_amdgcn_mfma_f32_16x16x32_bf16(a[mf], b[nf], acc[mf][nf], 0, 0, 0);
    __syncthreads();
  }
#undef QSTAGE

  const int wsel = n0 >> 10;
  const float* bias = (wsel == 0) ? bq : (wsel == 1) ? bk : bv;
  if (wsel == 2) {
    // V^T epilogue: vt[bh][d][kv], vectorized 4x bf16 along kv
    unsigned short* vt = qkv + (size_t)2 * QSZ;
    #pragma unroll
    for (int nf = 0; nf < 4; ++nf) {
      int ncl = (n0 + wn + nf * 16 + l15) & 1023;
      float bv_ = bias[ncl];
      int h = ncl >> 8, d = ncl & 255;
      #pragma unroll
      for (int mf = 0; mf < 4; ++mf) {
        int mrow0 = m0 + wm + mf * 16 + l4 * 4;
        int bb = mrow0 >> 11, nn0 = mrow0 & 2047;
        ushort4v o;
        #pragma unroll
        for (int e = 0; e < 4; ++e) o[e] = f2bf(acc[mf][nf][e] + bv_);
        *(ushort4v*)&vt[((size_t)((bb * 4 + h) * 256 + d)) * 2048 + nn0] = o;
      }
    }
  } else {
    // Q: 1/sqrt(256) * log2(e)  (exp2-domain softmax downstream)
    const float scale = (wsel == 0) ? 0.0625f * 1.44269504f : 1.0f;
    unsigned short* dst = qkv + (size_t)wsel * QSZ;
    #pragma unroll
    for (int nf = 0; nf < 4; ++nf) {
      int ncl = (n0 + wn + nf * 16 + l15) & 1023;
      float bv_ = bias[ncl];
      int h = ncl >> 8, d = ncl & 255;
      #pragma unroll
      for (int mf = 0; mf < 4; ++mf)
        #pragma unroll
        for (int e = 0; e < 4; ++e) {
          int mrow = m0 + wm + mf * 16 + l4 * 4 + e;
          int bb = mrow >> 11, nn = mrow & 2047;
          dst[((size_t)(bb * 4 + h) * 2048 + nn) * 256 + d] =
              f2bf((acc[mf][nf][e] + bv_) * scale);
        }
    }
  }
}

// ---------------------------------------------------------------------------
// Kernel 2: flash attention, 32x32x16 MFMA, 2 blocks/CU (R12 structure).
// R14: K staging = pure global_load_lds DMA with source swizzle (fixed tile
// stride: 16384 BYTES = 32 rows x 512 B, was wrongly 32768 in R13).
// LDS image identical to R12's reg-stage: cell (r,u) holds natural unit
// u ^ (r&7).  4 waves x 32 q-rows, KVBLK=32, 64 KB dynamic LDS.
// Output written in place over the block's own Q rows.
// ---------------------------------------------------------------------------
__global__ __launch_bounds__(256, 2) void attn_fused(
    unsigned short* __restrict__ qkv)
{
  extern __shared__ __align__(16) char smem[];   // 65536 bytes
  const int tid = threadIdx.x;
  const int lane = tid & 63, wid = tid >> 6;     // 4 waves
  const int l31 = lane & 31, hi = lane >> 5;

  const int id0 = blockIdx.x;                 // 0..511
  const int swzb = (id0 & 7) * 64 + (id0 >> 3);
  const int qt = swzb & 15, bh = swzb >> 4;   // 16 qt x 32 bh

  const unsigned short* Qh = qkv + (size_t)bh * (N_ * DH);
  const unsigned short* Kh = qkv + (size_t)QSZ + (size_t)bh * (N_ * DH);
  const unsigned short* Vt = qkv + (size_t)2 * QSZ + (size_t)bh * (N_ * DH);

  // Q fragments: lane provides q = q0+l31, d = st*16 + hi*8 + 0..7
  const int q0 = qt * 128 + wid * 32;
  short8v qf[16];
  #pragma unroll
  for (int st = 0; st < 16; ++st)
    qf[st] = *(const short8v*)(Qh + (size_t)(q0 + l31) * DH + st * 16 + hi * 8);

  // K staging source offsets (DMA, swizzle on source, linear dest):
  // dest unit U = j*256+tid; row r = U>>5, unit u = U&31;
  // source byte = r*512 + ((u ^ (r&7))<<4)
  int kgoff[4];
  #pragma unroll
  for (int j = 0; j < 4; ++j) {
    int U = j * 256 + tid;
    int r = U >> 5, u = U & 31;
    kgoff[j] = r * 512 + ((u ^ (r & 7)) << 4);
  }
  // V^T staging: linear LDS dest [256 d][32 kv]; source swizzled so that
  // LDS(row r, 16B-unit u) = global (r, u ^ (r&3)); rows are 4 units (64 B).
  int vgoff[4];
  #pragma unroll
  for (int j = 0; j < 4; ++j) {
    int r = j * 64 + (tid >> 2);
    int u = tid & 3;
    vgoff[j] = r * 4096 + ((u ^ (r & 3)) << 4);
  }

  // read bases
  const int dswz = (l31 & 7) << 4;
  const int krow0 = l31 * 512;
  int vbs[2];
  #pragma unroll
  for (int s = 0; s < 2; ++s)
    vbs[s] = l31 * 64 + (((s * 2 + hi) ^ (l31 & 3)) << 4);

  f32x16 ot[8] = {};
  float mr = -1.0e30f, lp = 0.0f;

#define KBUF(b) (smem + (b) * 16384)
#define VBUF(b) (smem + 32768 + (b) * 16384)
#define BMF32 __builtin_amdgcn_mfma_f32_32x32x16_bf16

#define STAGE(t, b) do {                                                     \
    const char* kg = (const char*)Kh + (size_t)(t) * 16384;                  \
    const char* vg = (const char*)Vt + (size_t)(t) * 64;                     \
    _Pragma("unroll")                                                        \
    for (int j = 0; j < 4; ++j) {                                            \
      gload_lds16(kg + kgoff[j], KBUF(b) + j * 4096 + tid * 16);             \
      gload_lds16(vg + vgoff[j], VBUF(b) + j * 4096 + tid * 16);             \
    }                                                                        \
  } while (0)

  union UPK { unsigned u[4]; short8v v; };

  // prologue: stage tile 0
  STAGE(0, 0);
  __syncthreads();

  for (int t = 0; t < 64; ++t) {
    const int cur = t & 1;
    if (t < 63) STAGE(t + 1, cur ^ 1);      // fire-and-forget DMA

    // ---- QK^T: S^T = K . Q^T, 1 kv-frag x 16 d-steps = 16 MFMAs ----
    const char* Kc = KBUF(cur);
    f32x16 sa = {};
    __builtin_amdgcn_s_setprio(1);
    #pragma unroll
    for (int st = 0; st < 16; ++st) {
      int off = (st * 32 + hi * 16) ^ dswz;
      short8v a0 = *(const short8v*)(Kc + krow0 + off);
      sa = BMF32(a0, qf[st], sa, 0, 0, 0);
    }
    __builtin_amdgcn_s_setprio(0);

    // ---- online softmax (exp2 domain, row-local, 1-hop exchange) ----
    float tm = sa[0];
    #pragma unroll
    for (int i = 1; i < 16; ++i) tm = fmaxf(tm, sa[i]);
    tm = fmaxf(tm, __shfl_xor(tm, 32));
    if (__any(tm > mr + 11.54f)) {          // defer-max (8 nats in exp2 dom)
      float mn = fmaxf(mr, tm), al = exp2f(mr - mn);
      lp *= al;
      #pragma unroll
      for (int df = 0; df < 8; ++df) ot[df] *= al;
      mr = mn;
    }
    #pragma unroll
    for (int i = 0; i < 16; ++i) sa[i] = exp2f(sa[i] - mr);
    #pragma unroll
    for (int i = 0; i < 16; ++i) lp += sa[i];

    // ---- P -> PV B-frags: cvt_pk + permlane32_swap (T12) ----
    short8v pb0, pb1;
    {
      unsigned x0 = cvtpk(sa[0], sa[1]),  y0 = cvtpk(sa[4], sa[5]);
      unsigned x1 = cvtpk(sa[2], sa[3]),  y1 = cvtpk(sa[6], sa[7]);
      unsigned x2 = cvtpk(sa[8], sa[9]),  y2 = cvtpk(sa[12], sa[13]);
      unsigned x3 = cvtpk(sa[10], sa[11]), y3 = cvtpk(sa[14], sa[15]);
      asm("v_permlane32_swap_b32 %0, %1" : "+v"(x0), "+v"(y0));
      asm("v_permlane32_swap_b32 %0, %1" : "+v"(x1), "+v"(y1));
      asm("v_permlane32_swap_b32 %0, %1" : "+v"(x2), "+v"(y2));
      asm("v_permlane32_swap_b32 %0, %1" : "+v"(x3), "+v"(y3));
      UPK u0; u0.u[0] = x0; u0.u[1] = x1; u0.u[2] = y0; u0.u[3] = y1; pb0 = u0.v;
      UPK u1; u1.u[0] = x2; u1.u[1] = x3; u1.u[2] = y2; u1.u[3] = y3; pb1 = u1.v;
    }

    // ---- PV: O^T += V^T . P^T, 8 d-frags x 2 kv-steps = 16 MFMAs ----
    const char* Vc = VBUF(cur);
    __builtin_amdgcn_s_setprio(1);
    #pragma unroll
    for (int df = 0; df < 8; ++df) {
      const char* vr = Vc + df * 2048;
      short8v v0 = *(const short8v*)(vr + vbs[0]);
      short8v v1 = *(const short8v*)(vr + vbs[1]);
      ot[df] = BMF32(v0, pb0, ot[df], 0, 0, 0);
      ot[df] = BMF32(v1, pb1, ot[df], 0, 0, 0);
    }
    __builtin_amdgcn_s_setprio(0);

    __syncthreads();   // drains vmcnt: tile t+1 staged & visible
  }

  // ---- epilogue: combine psum halves, normalize, overwrite own Q rows ----
  lp += __shfl_xor(lp, 32);
  float inv = 1.0f / lp;
  unsigned short* Oq = (unsigned short*)Qh;
  size_t base = (size_t)(q0 + l31) * DH;
  #pragma unroll
  for (int df = 0; df < 8; ++df) {
    #pragma unroll
    for (int j = 0; j < 4; ++j) {
      int d = df * 32 + j * 8 + hi * 4;
      ushort4v o;
      #pragma unroll
      for (int e = 0; e < 4; ++e) o[e] = f2bf(ot[df][j * 4 + e] * inv);
      *(ushort4v*)&Oq[base + d] = o;
    }
  }
#undef STAGE
#undef KBUF
#undef VBUF
#undef BMF32
}

// ---------------------------------------------------------------------------
// Kernel 3: out[16384][256] = attnO @ Wo + bo.  attnO is in the Q region,
// layout [B,H,N,DH]; logical row m = bb*2048+q, col k = h*256+d.
// 64m x 256n tiles -> 256 blocks (all CUs), 4 waves, 40 KB LDS.
// ---------------------------------------------------------------------------
__global__ __launch_bounds__(256) void out_gemm3(
    const unsigned short* __restrict__ Aq, const unsigned short* __restrict__ WoT,
    const float* __restrict__ bo, float* __restrict__ out)
{
  __shared__ __align__(16) unsigned short Ab[2][2048];   // [64][32] bf16
  __shared__ __align__(16) unsigned short Bb[2][8192];   // [256][32] bf16
  const int tid = threadIdx.x;
  const int lane = tid & 63, wid = tid >> 6;   // 4 waves
  const int l15 = lane & 15, l4 = lane >> 4;
  const int m0 = blockIdx.x * 64;
  const int wn = wid * 64;
  const int bb = m0 >> 11;
  const int qbase = m0 & 2047;
  const int sr = lane >> 2, sc = lane & 3;

  f32x4 acc[4][4] = {};

#define OSTAGE(t, b) do {                                                    \
    int h = (t) >> 3;                                                        \
    int d0 = ((t) & 7) * 32 + sc * 8;                                        \
    gload_lds16(Aq + ((size_t)(bb * 4 + h) * 2048 + qbase + wid * 16 + sr)   \
                         * 256 + d0,                                         \
                (char*)&Ab[b][0] + wid * 1024);                              \
    _Pragma("unroll")                                                        \
    for (int i = 0; i < 4; ++i) {                                            \
      int br = wid * 64 + i * 16 + sr;                                       \
      gload_lds16((const char*)WoT + (size_t)br * 2048 + (t) * 64 + sc * 16, \
                  (char*)&Bb[b][0] + (wid * 4 + i) * 1024);                  \
    }                                                                        \
  } while (0)

  OSTAGE(0, 0);
  __syncthreads();

  for (int t = 0; t < 32; ++t) {
    const int cur = t & 1;
    if (t < 31) OSTAGE(t + 1, cur ^ 1);
    short8v a[4], b[4];
    #pragma unroll
    for (int mf = 0; mf < 4; ++mf)
      a[mf] = *(const short8v*)((const char*)&Ab[cur][0] +
                                (mf * 16 + l15) * 64 + l4 * 16);
    #pragma unroll
    for (int nf = 0; nf < 4; ++nf)
      b[nf] = *(const short8v*)((const char*)&Bb[cur][0] +
                                (wn + nf * 16 + l15) * 64 + l4 * 16);
    #pragma unroll
    for (int mf = 0; mf < 4; ++mf)
      #pragma unroll
      for (int nf = 0; nf < 4; ++nf)
        acc[mf][nf] = __builtin_amdgcn_mfma_f32_16x16x32_bf16(a[mf], b[nf], acc[mf][nf], 0, 0, 0);
    __syncthreads();
  }
#undef OSTAGE

  #pragma unroll
  for (int nf = 0; nf < 4; ++nf) {
    int ncol = wn + nf * 16 + l15;
    float bv_ = bo[ncol];
    #pragma unroll
    for (int mf = 0; mf < 4; ++mf)
      #pragma unroll
      for (int e = 0; e < 4; ++e) {
        int mrow = m0 + mf * 16 + l4 * 4 + e;
        out[(size_t)mrow * 256 + ncol] = acc[mf][nf][e] + bv_;
      }
  }
}

// ---------------------------------------------------------------------------
extern "C" void kernel_launch(void* const* d_in, const int* in_sizes, int n_in,
                              void* d_out, int out_size, void* d_ws, size_t ws_size,
                              hipStream_t stream) {
  const float* x  = (const float*)d_in[0];
  const float* Wq = (const float*)d_in[1];
  const float* bq = (const float*)d_in[2];
  const float* Wk = (const float*)d_in[3];
  const float* bk = (const float*)d_in[4];
  const float* Wv = (const float*)d_in[5];
  const float* bv = (const float*)d_in[6];
  const float* Wo = (const float*)d_in[7];
  const float* bo = (const float*)d_in[8];

  unsigned short* qkvbuf = (unsigned short*)d_ws;       // Q|K|V^T bf16 (96 MiB)
  unsigned short* Wt     = qkvbuf + (size_t)3 * QSZ;    // [3328][1024] bf16
  float* out = (float*)d_out;

  prep_wt  <<<dim3(52, 16), 256, 0, stream>>>(Wq, Wk, Wv, Wo, Wt);
  qkv_gemm2<<<dim3(1536),   512, 0, stream>>>(x, Wt, bq, bk, bv, qkvbuf);
  attn_fused<<<dim3(512),   256, 65536, stream>>>(qkvbuf);
  out_gemm3<<<dim3(256),    256, 0, stream>>>(qkvbuf, Wt + (size_t)3072 * 1024, bo, out);
}